// Round 5
// baseline (5271.705 us; speedup 1.0000x reference)
//
#include <hip/hip_runtime.h>

#define D 32
#define K_CODES 8192
#define ROWS_PB 16
#define TPB 256
#define HALFK 4096            // second code of each thread: k0 + HALFK
#define JITERS 16             // K_CODES / (2 * TPB)

// Map float -> unsigned such that unsigned order == float order (all floats).
__device__ __forceinline__ unsigned sortkey(float f) {
    unsigned b = __float_as_uint(f);
    return b ^ ((unsigned)((int)b >> 31) | 0x80000000u);
}

__global__ __launch_bounds__(TPB, 4) void vq_main(
    const float* __restrict__ x, const float* __restrict__ cb,
    float* __restrict__ out, unsigned* __restrict__ minD,
    unsigned* __restrict__ used, float* __restrict__ mse_accum)
{
    __shared__ float4 xs4[ROWS_PB][8];           // 16 rows x 32 dims, b128-aligned
    __shared__ float xx[ROWS_PB];
    __shared__ unsigned tokS[ROWS_PB];
    __shared__ unsigned long long wbest[4][ROWS_PB];
    __shared__ float pp[4];

    const int tid = threadIdx.x;
    const long row0 = (long)blockIdx.x * ROWS_PB;

    // Stage 16 rows (2 KB) into LDS, coalesced float4.
    if (tid < ROWS_PB * D / 4)
        ((float4*)xs4)[tid] = ((const float4*)(x + row0 * D))[tid];
    __syncthreads();
    if (tid < ROWS_PB) {
        float s = 0.f;
        const float* xr = (const float*)xs4[tid];
        #pragma unroll
        for (int d = 0; d < D; ++d) s += xr[d] * xr[d];
        xx[tid] = s;
    }
    __syncthreads();

    // Per-row running best score / index (this thread's codes only).
    float bs[ROWS_PB];
    int   bi[ROWS_PB];
    #pragma unroll
    for (int r = 0; r < ROWS_PB; ++r) { bs[r] = -3.0e38f; bi[r] = 0; }

    const float4* cb4 = (const float4*)cb;

    for (int j = 0; j < JITERS; ++j) {
        const int k0 = tid + j * TPB;            // [0, 4096)
        const int k1 = k0 + HALFK;
        // 2 codes in registers: 64 VGPRs.
        float4 c0[8], c1[8];
        {
            const float4* p0 = cb4 + (long)k0 * 8;
            const float4* p1 = cb4 + (long)k1 * 8;
            #pragma unroll
            for (int w = 0; w < 8; ++w) { c0[w] = p0[w]; c1[w] = p1[w]; }
        }
        float C0 = 0.f, C1 = 0.f;
        #pragma unroll
        for (int w = 0; w < 8; ++w) {
            C0 += c0[w].x*c0[w].x + c0[w].y*c0[w].y + c0[w].z*c0[w].z + c0[w].w*c0[w].w;
            C1 += c1[w].x*c1[w].x + c1[w].y*c1[w].y + c1[w].z*c1[w].z + c1[w].w*c1[w].w;
        }
        float md0 = 3.0e38f, md1 = 3.0e38f;

        #pragma unroll
        for (int r = 0; r < ROWS_PB; ++r) {
            float dot0 = 0.f, dot1 = 0.f;
            #pragma unroll
            for (int w = 0; w < 8; ++w) {
                const float4 xv = xs4[r][w];     // uniform-address b128 broadcast
                dot0 += c0[w].x*xv.x; dot0 += c0[w].y*xv.y;
                dot0 += c0[w].z*xv.z; dot0 += c0[w].w*xv.w;
                dot1 += c1[w].x*xv.x; dot1 += c1[w].y*xv.y;
                dot1 += c1[w].z*xv.z; dot1 += c1[w].w*xv.w;
            }
            // score s = 2*x.c - ||c||^2 ; argmin dist == argmax s (||x||^2 common)
            const float s0 = 2.f*dot0 - C0;
            const float s1 = 2.f*dot1 - C1;
            // strict > prefers smaller k within the pair (k0 < k1)
            float ma = s0; int ka = k0;
            if (s1 > ma) { ma = s1; ka = k1; }
            // cross-j: exact ties must keep smallest k (k order is not monotone in j)
            if (ma > bs[r] || (ma == bs[r] && ka < bi[r])) { bs[r] = ma; bi[r] = ka; }
            // entropy-loss per-code min distance (dist = ||x||^2 - s, always > 0)
            const float xxr = xx[r];
            md0 = fminf(md0, xxr - s0);
            md1 = fminf(md1, xxr - s1);
        }
        atomicMin(&minD[k0], __float_as_uint(md0));
        atomicMin(&minD[k1], __float_as_uint(md1));
    }

    // Block-level per-row argmax reduce: pack to u64 once, shuffle tree, LDS across waves.
    const int lane = tid & 63;
    const int wid = tid >> 6;
    #pragma unroll
    for (int r = 0; r < ROWS_PB; ++r) {
        unsigned long long b =
            ((unsigned long long)sortkey(bs[r]) << 32) | (unsigned)(~bi[r]);
        #pragma unroll
        for (int off = 32; off > 0; off >>= 1) {
            unsigned long long o = __shfl_xor(b, off, 64);
            if (o > b) b = o;
        }
        if (lane == 0) wbest[wid][r] = b;
    }
    __syncthreads();
    if (tid < ROWS_PB) {
        unsigned long long b = wbest[0][tid];
        if (wbest[1][tid] > b) b = wbest[1][tid];
        if (wbest[2][tid] > b) b = wbest[2][tid];
        if (wbest[3][tid] > b) b = wbest[3][tid];
        unsigned tok = ~(unsigned)(b & 0xFFFFFFFFull);
        tokS[tid] = tok;
        used[tok] = 1u;   // benign race: all writers store 1
    }
    __syncthreads();

    // Emit emb (== straight-through output values) + fused MSE partial.
    float part = 0.f;
    for (int i = tid; i < ROWS_PB * D; i += TPB) {
        int r = i >> 5, d = i & 31;
        float e = cb[(long)tokS[r] * D + d];
        out[(row0 + r) * D + d] = e;
        float dx = e - ((const float*)xs4[r])[d];
        part += dx * dx;
    }
    #pragma unroll
    for (int off = 32; off > 0; off >>= 1) part += __shfl_xor(part, off, 64);
    if (lane == 0) pp[wid] = part;
    __syncthreads();
    if (tid == 0) atomicAdd(mse_accum, pp[0] + pp[1] + pp[2] + pp[3]);
}

__global__ __launch_bounds__(TPB) void vq_finish(
    const unsigned* __restrict__ minD, const unsigned* __restrict__ used,
    const float* __restrict__ mse_accum, float* __restrict__ out, int n_elems)
{
    __shared__ float pp[4];
    const int tid = threadIdx.x;
    float s = 0.f;
    for (int k = tid; k < K_CODES; k += TPB)
        if (used[k] == 0u) s += __uint_as_float(minD[k]);
    const int lane = tid & 63;
    const int wid = tid >> 6;
    #pragma unroll
    for (int off = 32; off > 0; off >>= 1) s += __shfl_xor(s, off, 64);
    if (lane == 0) pp[wid] = s;
    __syncthreads();
    if (tid == 0) {
        float ent = (pp[0] + pp[1] + pp[2] + pp[3]) / (float)K_CODES;
        float mse = mse_accum[0] / (float)n_elems;
        // embedding(1.0) + commitment(0.25) share the same value; entropy w=0.1
        out[n_elems] = 1.25f * mse + 0.1f * ent;
    }
}

extern "C" void kernel_launch(void* const* d_in, const int* in_sizes, int n_in,
                              void* d_out, int out_size, void* d_ws, size_t ws_size,
                              hipStream_t stream)
{
    (void)n_in; (void)out_size; (void)ws_size;
    const float* x  = (const float*)d_in[0];
    const float* cb = (const float*)d_in[1];
    float* out = (float*)d_out;
    const int n_elems = in_sizes[0];           // 524288
    const int nrows   = n_elems / D;           // 16384

    unsigned* minD      = (unsigned*)d_ws;
    unsigned* used      = (unsigned*)((char*)d_ws + K_CODES * 4);
    float*    mse_accum = (float*)   ((char*)d_ws + K_CODES * 8);

    hipMemsetAsync(minD, 0x7F, K_CODES * 4, stream);  // 0x7F7F7F7F = 3.39e38 (+inf proxy)
    hipMemsetAsync(used, 0, K_CODES * 4, stream);
    hipMemsetAsync(mse_accum, 0, 4, stream);

    vq_main<<<nrows / ROWS_PB, TPB, 0, stream>>>(x, cb, out, minD, used, mse_accum);
    vq_finish<<<1, TPB, 0, stream>>>(minD, used, mse_accum, out, n_elems);
}

// Round 6
// 385.170 us; speedup vs baseline: 13.6867x; 13.6867x over previous
//
#include <hip/hip_runtime.h>

#define D 32
#define K_CODES 8192
#define N_ROWS 16384
#define TPB 256
#define ROWS_PER_T 2
#define ROWS_PB (TPB * ROWS_PER_T)       // 512 rows per block
#define ROW_GROUPS (N_ROWS / ROWS_PB)    // 32
#define SPLITS 32
#define KPB (K_CODES / SPLITS)           // 256 codes per block

// ws layout (bytes)
#define WS_ROWBEST 0                      // u64 x 16384 = 131072
#define WS_USED    131072                 // u32 x 8192  = 32768
#define WS_MSE     163840                 // f32 x 1
#define WS_MIND    163844                 // u32 x 8192  = 32768
#define WS_NHC     196612                 // f32 x 8192  = 32768

// Map float -> unsigned such that unsigned order == float order.
__device__ __forceinline__ unsigned sortkey(float f) {
    unsigned b = __float_as_uint(f);
    return b ^ ((unsigned)((int)b >> 31) | 0x80000000u);
}

// One DPP min step: v = min(v, dpp_move(v)). bound_ctrl=false + row_mask keeps
// non-receiving lanes at old value (harmless self-min).
template <int CTRL, int RMASK>
__device__ __forceinline__ float dppmin(float v) {
    int m = __builtin_amdgcn_update_dpp(__float_as_int(v), __float_as_int(v),
                                        CTRL, RMASK, 0xF, false);
    return fminf(v, __int_as_float(m));
}

// Pass 0: negHalfC[k] = -0.5 * ||c_k||^2
__global__ __launch_bounds__(TPB) void vq_nhc(const float* __restrict__ cb,
                                              float* __restrict__ nhc) {
    const int k = blockIdx.x * TPB + threadIdx.x;
    const float4* p = (const float4*)cb + (size_t)k * 8;
    float s = 0.f;
    #pragma unroll
    for (int w = 0; w < 8; ++w) {
        float4 v = p[w];
        s += v.x * v.x + v.y * v.y + v.z * v.z + v.w * v.w;
    }
    nhc[k] = -0.5f * s;
}

// Pass 1: rows in registers (2/thread, scalar argmax state), codes streamed
// as wave-uniform global loads. Per-code min over rows via DPP butterfly.
__global__ __launch_bounds__(TPB) void vq_dist(
    const float* __restrict__ x, const float* __restrict__ cb,
    const float* __restrict__ nhc,
    unsigned long long* __restrict__ rowBest, unsigned* __restrict__ minD)
{
    const int tid = threadIdx.x;
    const int rg  = blockIdx.x & (ROW_GROUPS - 1);
    const int sp  = blockIdx.x >> 5;              // / ROW_GROUPS
    const int r0  = rg * ROWS_PB + tid;
    const int r1  = r0 + TPB;
    const int kbase = sp * KPB;

    // Own rows -> registers (coalesced float4 loads).
    float4 x0[8], x1[8];
    {
        const float4* xp0 = (const float4*)x + (size_t)r0 * 8;
        const float4* xp1 = (const float4*)x + (size_t)r1 * 8;
        #pragma unroll
        for (int w = 0; w < 8; ++w) { x0[w] = xp0[w]; x1[w] = xp1[w]; }
    }
    float xx0 = 0.f, xx1 = 0.f;
    #pragma unroll
    for (int w = 0; w < 8; ++w) {
        xx0 += x0[w].x*x0[w].x + x0[w].y*x0[w].y + x0[w].z*x0[w].z + x0[w].w*x0[w].w;
        xx1 += x1[w].x*x1[w].x + x1[w].y*x1[w].y + x1[w].z*x1[w].z + x1[w].w*x1[w].w;
    }

    float bs0 = -3.0e38f, bs1 = -3.0e38f;
    int   bi0 = 0,        bi1 = 0;

    const float4* cbp  = (const float4*)cb + (size_t)kbase * 8;
    const float*  nhcp = nhc + kbase;

    #pragma unroll 2
    for (int kk = 0; kk < KPB; ++kk) {
        // t = dot(x, c_k) - ||c_k||^2/2 ; argmax t == argmin dist (2t = score)
        float t0 = nhcp[kk];              // uniform load
        float t1 = t0;
        #pragma unroll
        for (int w = 0; w < 8; ++w) {
            const float4 cv = cbp[(size_t)kk * 8 + w];   // uniform 16B load
            t0 += cv.x*x0[w].x; t0 += cv.y*x0[w].y;
            t0 += cv.z*x0[w].z; t0 += cv.w*x0[w].w;
            t1 += cv.x*x1[w].x; t1 += cv.y*x1[w].y;
            t1 += cv.z*x1[w].z; t1 += cv.w*x1[w].w;
        }
        const int kg = kbase + kk;
        // strict > with ascending kg keeps smallest index on exact ties
        if (t0 > bs0) { bs0 = t0; bi0 = kg; }
        if (t1 > bs1) { bs1 = t1; bi1 = kg; }
        // dist = ||x||^2 - 2t  (>= ~28 for this data; float-bit order valid)
        float m = fminf(__builtin_fmaf(-2.f, t0, xx0),
                        __builtin_fmaf(-2.f, t1, xx1));
        // full-wave min -> lane 63 (VALU-pipe DPP butterfly)
        m = dppmin<0xB1,  0xF>(m);   // quad_perm [1,0,3,2]  (xor1)
        m = dppmin<0x4E,  0xF>(m);   // quad_perm [2,3,0,1]  (xor2)
        m = dppmin<0x141, 0xF>(m);   // row_half_mirror      (8-group)
        m = dppmin<0x140, 0xF>(m);   // row_mirror           (16-group)
        m = dppmin<0x142, 0xA>(m);   // row_bcast15 -> rows 1,3
        m = dppmin<0x143, 0xC>(m);   // row_bcast31 -> rows 2,3
        if ((tid & 63) == 63)
            atomicMin(&minD[kg], __float_as_uint(m));
    }

    // Publish per-row best across code-splits: packed (sortkey(t)<<32)|~k.
    unsigned long long p0 = ((unsigned long long)sortkey(bs0) << 32) | (unsigned)(~bi0);
    unsigned long long p1 = ((unsigned long long)sortkey(bs1) << 32) | (unsigned)(~bi1);
    atomicMax(&rowBest[r0], p0);
    atomicMax(&rowBest[r1], p1);
}

// Pass 2: finalize tokens -> gather emb, write out, fused MSE, mark used.
__global__ __launch_bounds__(TPB) void vq_emit(
    const float* __restrict__ x, const float* __restrict__ cb,
    const unsigned long long* __restrict__ rowBest,
    unsigned* __restrict__ used, float* __restrict__ mse,
    float* __restrict__ out)
{
    const int r = blockIdx.x * TPB + threadIdx.x;
    const unsigned tok = ~(unsigned)(rowBest[r] & 0xFFFFFFFFull);
    used[tok] = 1u;                        // benign race: all writers store 1
    const float4* e4 = (const float4*)cb + (size_t)tok * 8;
    const float4* x4 = (const float4*)x + (size_t)r * 8;
    float4* o4 = (float4*)out + (size_t)r * 8;
    float part = 0.f;
    #pragma unroll
    for (int w = 0; w < 8; ++w) {
        float4 e = e4[w], xv = x4[w];
        o4[w] = e;
        float a = e.x - xv.x; part += a * a;
        a = e.y - xv.y; part += a * a;
        a = e.z - xv.z; part += a * a;
        a = e.w - xv.w; part += a * a;
    }
    #pragma unroll
    for (int off = 32; off > 0; off >>= 1) part += __shfl_xor(part, off, 64);
    if ((threadIdx.x & 63) == 0) atomicAdd(mse, part);
}

// Pass 3: entropy over unused codes + total loss scalar.
__global__ __launch_bounds__(TPB) void vq_finish(
    const unsigned* __restrict__ minD, const unsigned* __restrict__ used,
    const float* __restrict__ mse, float* __restrict__ out, int n_elems)
{
    __shared__ float pp[4];
    const int tid = threadIdx.x;
    float s = 0.f;
    for (int k = tid; k < K_CODES; k += TPB)
        if (used[k] == 0u) s += __uint_as_float(minD[k]);
    #pragma unroll
    for (int off = 32; off > 0; off >>= 1) s += __shfl_xor(s, off, 64);
    const int lane = tid & 63, wid = tid >> 6;
    if (lane == 0) pp[wid] = s;
    __syncthreads();
    if (tid == 0) {
        float ent = (pp[0] + pp[1] + pp[2] + pp[3]) / (float)K_CODES;
        float m = mse[0] / (float)n_elems;
        out[n_elems] = 1.25f * m + 0.1f * ent;   // embedding+commitment+entropy
    }
}

extern "C" void kernel_launch(void* const* d_in, const int* in_sizes, int n_in,
                              void* d_out, int out_size, void* d_ws, size_t ws_size,
                              hipStream_t stream)
{
    (void)n_in; (void)out_size; (void)ws_size;
    const float* x  = (const float*)d_in[0];
    const float* cb = (const float*)d_in[1];
    float* out = (float*)d_out;
    const int n_elems = in_sizes[0];                 // 524288

    char* ws = (char*)d_ws;
    unsigned long long* rowBest = (unsigned long long*)(ws + WS_ROWBEST);
    unsigned* used = (unsigned*)(ws + WS_USED);
    float*    mse  = (float*)   (ws + WS_MSE);
    unsigned* minD = (unsigned*)(ws + WS_MIND);
    float*    nhc  = (float*)   (ws + WS_NHC);

    // rowBest(0) + used(0) + mse(0) in one memset; minD to +inf-proxy.
    hipMemsetAsync(ws, 0, WS_MSE + 4, stream);
    hipMemsetAsync(ws + WS_MIND, 0x7F, K_CODES * 4, stream);   // 3.39e38

    vq_nhc <<<K_CODES / TPB, TPB, 0, stream>>>(cb, nhc);
    vq_dist<<<ROW_GROUPS * SPLITS, TPB, 0, stream>>>(x, cb, nhc, rowBest, minD);
    vq_emit<<<N_ROWS / TPB, TPB, 0, stream>>>(x, cb, rowBest, used, mse, out);
    vq_finish<<<1, TPB, 0, stream>>>(minD, used, mse, out, n_elems);
}